// Round 9
// baseline (1293.299 us; speedup 1.0000x reference)
//
#include <hip/hip_runtime.h>
#include <math.h>

typedef float v2f __attribute__((ext_vector_type(2)));

#define LN2_INV 1.4426950408889634f

__device__ __forceinline__ float fexp2(float x) {
#if __has_builtin(__builtin_amdgcn_exp2f)
    return __builtin_amdgcn_exp2f(x);
#else
    return exp2f(x);
#endif
}

__device__ __forceinline__ int rdlane_i(int v, int k) {
    return __builtin_amdgcn_readlane(v, k);
}

// packed f32 VOP3P, all-VGPR operands (assemble+numerics proven R4-R7)
__device__ __forceinline__ v2f pk_fma(v2f a, v2f b, v2f c) {
    asm("v_pk_fma_f32 %0, %1, %2, %0" : "+v"(c) : "v"(a), "v"(b));
    return c;
}
__device__ __forceinline__ v2f pk_mul(v2f a, v2f b) {
    v2f d;
    asm("v_pk_mul_f32 %0, %1, %2" : "=v"(d) : "v"(a), "v"(b));
    return d;
}

// v += dpp(v): row_ror rotate-accumulate; no invalid lanes for ror so
// bound_ctrl/old are don't-care. ror1/2/4/8 = full 16-lane all-reduce.
#define DPP_ADD(V, CTRL) \
    V += __int_as_float(__builtin_amdgcn_update_dpp(0, __float_as_int(V), CTRL, 0xf, 0xf, true));

// ---------------------------------------------------------------------------
// k_h0: h0 = relu(x @ f_W + f_b), x [N,128], f_W [128,64]. 8 nodes/block.
// ---------------------------------------------------------------------------
__global__ __launch_bounds__(256) void k_h0(const float* __restrict__ x,
                                            const float* __restrict__ fW,
                                            const float* __restrict__ fb,
                                            float* __restrict__ h0) {
    __shared__ __align__(16) float xs[8 * 128];
    int t = threadIdx.x;
    int base = blockIdx.x * 8;
#pragma unroll
    for (int r = 0; r < 4; ++r) { int j = r * 256 + t; xs[j] = x[base * 128 + j]; }
    __syncthreads();
    int c = t & 63, half = t >> 6;
    float acc0 = fb[c], acc1 = fb[c];
    int m0 = half, m1 = half + 4;
#pragma unroll 8
    for (int k0 = 0; k0 < 128; k0 += 4) {
        float4 a = *(const float4*)&xs[m0 * 128 + k0];
        float4 b = *(const float4*)&xs[m1 * 128 + k0];
        float w0 = fW[(k0 + 0) * 64 + c], w1 = fW[(k0 + 1) * 64 + c];
        float w2 = fW[(k0 + 2) * 64 + c], w3 = fW[(k0 + 3) * 64 + c];
        acc0 = fmaf(a.x, w0, fmaf(a.y, w1, fmaf(a.z, w2, fmaf(a.w, w3, acc0))));
        acc1 = fmaf(b.x, w0, fmaf(b.y, w1, fmaf(b.z, w2, fmaf(b.w, w3, acc1))));
    }
    h0[(base + m0) * 64 + c] = fmaxf(acc0, 0.f);
    h0[(base + m1) * 64 + c] = fmaxf(acc1, 0.f);
}

// ---------------------------------------------------------------------------
// k_xlxr: xl = h@Wl + bl, xr = h@Wr + br, natural [N][256] layout (h*64+d).
// ---------------------------------------------------------------------------
__global__ __launch_bounds__(256) void k_xlxr(const float* __restrict__ h,
                                              const float* __restrict__ Wl,
                                              const float* __restrict__ Wr,
                                              const float* __restrict__ bl,
                                              const float* __restrict__ br,
                                              float* __restrict__ xl,
                                              float* __restrict__ xr) {
    __shared__ __align__(16) float hs[16 * 64];
    int t = threadIdx.x;
    int base = blockIdx.x * 16;
#pragma unroll
    for (int r = 0; r < 4; ++r) hs[r * 256 + t] = h[base * 64 + r * 256 + t];
    __syncthreads();
    float bL = bl[t], bR = br[t];
    float accl[16], accr[16];
#pragma unroll
    for (int m = 0; m < 16; ++m) { accl[m] = bL; accr[m] = bR; }
#pragma unroll 4
    for (int k0 = 0; k0 < 64; k0 += 4) {
        float wl[4], wr[4];
#pragma unroll
        for (int q = 0; q < 4; ++q) {
            wl[q] = Wl[(k0 + q) * 256 + t];
            wr[q] = Wr[(k0 + q) * 256 + t];
        }
#pragma unroll
        for (int m = 0; m < 16; ++m) {
            float4 hv = *(const float4*)&hs[m * 64 + k0];
            accl[m] = fmaf(hv.x, wl[0], fmaf(hv.y, wl[1], fmaf(hv.z, wl[2], fmaf(hv.w, wl[3], accl[m]))));
            accr[m] = fmaf(hv.x, wr[0], fmaf(hv.y, wr[1], fmaf(hv.z, wr[2], fmaf(hv.w, wr[3], accr[m]))));
        }
    }
#pragma unroll
    for (int m = 0; m < 16; ++m) {
        xl[(base + m) * 256 + t] = accl[m];
        xr[(base + m) * 256 + t] = accr[m];
    }
}

// ---------------------------------------------------------------------------
// CSR build. rec record (stride 24 ints): [0..19] = relu edge-MLP s_k,
// [20] = src node, [21..23] pad. 4 zeroed pad records past E let the edge
// loop prefetch records unconditionally.
// ---------------------------------------------------------------------------
__global__ void k_zero(int* __restrict__ deg, int* __restrict__ counter,
                       int* __restrict__ rec, int Nn, int Ee) {
    int i = blockIdx.x * 256 + threadIdx.x;
    if (i < Nn) deg[i] = 0;
    if (i == 0) *counter = 0;
    if (blockIdx.x == 0 && threadIdx.x < 96) rec[(size_t)Ee * 24 + threadIdx.x] = 0;
}

__global__ void k_count(const int* __restrict__ dstArr, int* __restrict__ deg, int Ee) {
    int e = blockIdx.x * 256 + threadIdx.x;
    if (e < Ee) atomicAdd(&deg[dstArr[e]], 1);
}

__global__ void k_alloc(const int* __restrict__ deg, int* __restrict__ counter,
                        int* __restrict__ start, int* __restrict__ cursor, int Nn) {
    int n = blockIdx.x * 256 + threadIdx.x;
    if (n < Nn) {
        int d = deg[n];
        int b = atomicAdd(counter, d);
        start[n] = b;
        cursor[n] = b;
    }
}

__global__ void k_fill(const int* __restrict__ dstArr, const int* __restrict__ srcArr,
                       const float* __restrict__ eattr, const float* __restrict__ feW,
                       const float* __restrict__ feb, int* __restrict__ cursor,
                       int* __restrict__ rec, int Ee) {
    int e = blockIdx.x * 256 + threadIdx.x;
    if (e >= Ee) return;
    float a0 = eattr[2 * e], a1 = eattr[2 * e + 1];
    int p = atomicAdd(&cursor[dstArr[e]], 1);
    float* r = (float*)(rec + (size_t)p * 24);
    float s[20];
#pragma unroll
    for (int k = 0; k < 20; ++k)
        s[k] = fmaxf(fmaf(a0, feW[k], fmaf(a1, feW[20 + k], feb[k])), 0.f);
#pragma unroll
    for (int j = 0; j < 5; ++j)
        ((float4*)r)[j] = make_float4(s[4 * j], s[4 * j + 1], s[4 * j + 2], s[4 * j + 3]);
    ((int*)r)[20] = srcArr[e];
}

// ---------------------------------------------------------------------------
// k_edge: one wave per dst node (4 nodes / 256-thread block). Lane = h*16+g,
// holds dims 4g..4g+3 of head h (natural h*64+d order).
//  - Records read via UNIFORM-ADDRESS vector loads (5x float4, all lanes same
//    addr -> hardware dedups to one request, broadcast). Values land in VGPRs
//    already paired {s_2p,s_2p+1} for all-VGPR v_pk_fma_f32. No readlanes
//    (R7: 20/edge), no SMEM (R5: lgkm-drain stalls). vmcnt is in-order ->
//    counted waits + deep prefetch (sk A/B double-buffered, 1 pair ahead;
//    records sequential -> L1-hit).
//  - Score reduce: 4 DPP row_ror(1/2/4/8) adds = 16-lane all-reduce in
//    registers. ds_bpermute DELETED from the loop -> no lgkm ops in hot path.
//  - srcv: all <=64 src ids loaded once per node (lane-clamped strided load);
//    1 readlane/edge for gather addressing; xl gathers 2 pairs (~400cyc)
//    ahead. dn>64 falls back to a uniform load (negligible frequency).
// ---------------------------------------------------------------------------
#define VLOAD_REC(SK4, E_) do {                                              \
    const float4* _rp = (const float4*)(rf + (size_t)(E_) * 24);             \
    SK4[0] = _rp[0]; SK4[1] = _rp[1]; SK4[2] = _rp[2];                       \
    SK4[3] = _rp[3]; SK4[4] = _rp[4];                                        \
} while (0)

#define COMPUTE_EDGE(SK4, XL) do {                                           \
    v2f _a0, _a1, _a2, _a3;                                                  \
    {                                                                        \
        v2f _sp = {SK4[0].x, SK4[0].y};                                      \
        _a0 = pk_mul(_sp, weI0[0]);                                          \
        _a1 = pk_mul(_sp, weI1[0]);                                          \
        _a2 = pk_mul(_sp, weI2[0]);                                          \
        _a3 = pk_mul(_sp, weI3[0]);                                          \
    }                                                                        \
    _Pragma("unroll")                                                        \
    for (int _p = 1; _p < 10; ++_p) {                                        \
        int _j = _p >> 1;                                                    \
        v2f _sp = (_p & 1) ? (v2f){SK4[_j].z, SK4[_j].w}                     \
                           : (v2f){SK4[_j].x, SK4[_j].y};                    \
        _a0 = pk_fma(_sp, weI0[_p], _a0);                                    \
        _a1 = pk_fma(_sp, weI1[_p], _a1);                                    \
        _a2 = pk_fma(_sp, weI2[_p], _a2);                                    \
        _a3 = pk_fma(_sp, weI3[_p], _a3);                                    \
    }                                                                        \
    float _v0 = (XL.x + xrv.x) + (_a0.x + _a0.y);                            \
    float _v1 = (XL.y + xrv.y) + (_a1.x + _a1.y);                            \
    float _v2 = (XL.z + xrv.z) + (_a2.x + _a2.y);                            \
    float _v3 = (XL.w + xrv.w) + (_a3.x + _a3.y);                            \
    float _m0 = fmaxf(_v0, 0.2f * _v0);                                      \
    float _m1 = fmaxf(_v1, 0.2f * _v1);                                      \
    float _m2 = fmaxf(_v2, 0.2f * _v2);                                      \
    float _m3 = fmaxf(_v3, 0.2f * _v3);                                      \
    float _ps = fmaf(at0, _m0, fmaf(at1, _m1, fmaf(at2, _m2, at3 * _m3)));   \
    DPP_ADD(_ps, 0x121)                                                      \
    DPP_ADD(_ps, 0x122)                                                      \
    DPP_ADD(_ps, 0x124)                                                      \
    DPP_ADD(_ps, 0x128)                                                      \
    float _w = fexp2(_ps);                                                   \
    l += _w;                                                                 \
    v2f _w2 = {_w, _w};                                                      \
    v2f _xl01 = {XL.x, XL.y}, _xl23 = {XL.z, XL.w};                          \
    acc01 = pk_fma(_w2, _xl01, acc01);                                       \
    acc23 = pk_fma(_w2, _xl23, acc23);                                       \
} while (0)

__global__ __launch_bounds__(256, 3) void k_edge(
    const float4* __restrict__ xl4p, const float4* __restrict__ xr4p,
    const float* __restrict__ att, const float4* __restrict__ We4,
    const int* __restrict__ rec, const int* __restrict__ start,
    const int* __restrict__ deg, const float* __restrict__ bias,
    float* __restrict__ hout, int Nn) {
    const int lane = threadIdx.x & 63;
    const int n = (int)((blockIdx.x * 256u + threadIdx.x) >> 6);
    if (n >= Nn) return;

    const int dn = __builtin_amdgcn_readfirstlane(deg[n]);
    if (dn == 0) {
        if (lane < 16) {
            float4 b4 = ((const float4*)bias)[lane];
            float4 o = make_float4(fmaxf(b4.x, 0.f), fmaxf(b4.y, 0.f),
                                   fmaxf(b4.z, 0.f), fmaxf(b4.w, 0.f));
            ((float4*)hout)[(size_t)n * 16 + lane] = o;
        }
        return;
    }
    const int s0 = __builtin_amdgcn_readfirstlane(start[n]);
    const float* rf = (const float*)rec + (size_t)s0 * 24;  // uniform base
    const int* ri = rec + (size_t)s0 * 24;                  // uniform base

    // all src ids for this node in one strided load (lane-clamped)
    const int lc = (lane < dn) ? lane : (dn - 1);
    int srcv = rec[(size_t)(s0 + lc) * 24 + 20];

    // wave-invariant operands
    float4 attv = ((const float4*)att)[lane];
    float at0 = attv.x * LN2_INV, at1 = attv.y * LN2_INV;
    float at2 = attv.z * LN2_INV, at3 = attv.w * LN2_INV;
    float4 xrv = xr4p[(size_t)n * 64 + lane];
    // We, k-interleaved per dim: weI_d[p] = {We[2p][d], We[2p+1][d]}
    v2f weI0[10], weI1[10], weI2[10], weI3[10];
#pragma unroll
    for (int p = 0; p < 10; ++p) {
        float4 w0 = We4[(2 * p) * 64 + lane];
        float4 w1 = We4[(2 * p + 1) * 64 + lane];
        weI0[p].x = w0.x; weI0[p].y = w1.x;
        weI1[p].x = w0.y; weI1[p].y = w1.y;
        weI2[p].x = w0.z; weI2[p].y = w1.z;
        weI3[p].x = w0.w; weI3[p].y = w1.w;
    }

    v2f acc01 = {0.f, 0.f}, acc23 = {0.f, 0.f};
    float l = 0.f;

    // src for edge j (j pre-clamped to dn-1); dn>64 fallback = uniform load
    auto get_src = [&](int j) -> int {
        return (j < 64) ? rdlane_i(srcv, j) : ri[(size_t)j * 24 + 20];
    };

    // prologue: sk blocks 0,1; gathers for edges 0..3 (2 pairs deep)
    float4 skA4[5], skB4[5];
    VLOAD_REC(skA4, 0);
    VLOAD_REC(skB4, 1);
    int j1 = (1 < dn) ? 1 : (dn - 1);
    int j2 = (2 < dn) ? 2 : (dn - 1);
    int j3 = (3 < dn) ? 3 : (dn - 1);
    float4 xlA  = xl4p[(size_t)(unsigned)get_src(0) * 64 + lane];
    float4 xlB  = xl4p[(size_t)(unsigned)get_src(j1) * 64 + lane];
    float4 xlA1 = xl4p[(size_t)(unsigned)get_src(j2) * 64 + lane];
    float4 xlB1 = xl4p[(size_t)(unsigned)get_src(j3) * 64 + lane];

    const int nfull = dn >> 1;
    for (int t = 0; t < nfull; ++t) {
        int i = 2 * t;
        // gather prefetch for edges i+4, i+5 (consumed 2 iterations later)
        int jA = (i + 4 < dn) ? (i + 4) : (dn - 1);
        int jB = (i + 5 < dn) ? (i + 5) : (dn - 1);
        float4 xlA2 = xl4p[(size_t)(unsigned)get_src(jA) * 64 + lane];
        float4 xlB2 = xl4p[(size_t)(unsigned)get_src(jB) * 64 + lane];
        // compute pair; reload sk for pair t+1 (records sequential, L1-hit)
        COMPUTE_EDGE(skA4, xlA);
        VLOAD_REC(skA4, i + 2);
        COMPUTE_EDGE(skB4, xlB);
        VLOAD_REC(skB4, i + 3);
        xlA = xlA1; xlA1 = xlA2;
        xlB = xlB1; xlB1 = xlB2;
    }
    if (dn & 1) COMPUTE_EDGE(skA4, xlA);

    // epilogue: res = relu(bias + 0.25 * sum_h acc_h / l_h)
    float inv = 0.25f / l;
    float4 r = make_float4(acc01.x * inv, acc01.y * inv, acc23.x * inv, acc23.y * inv);
    r.x += __shfl_xor(r.x, 16, 64); r.x += __shfl_xor(r.x, 32, 64);
    r.y += __shfl_xor(r.y, 16, 64); r.y += __shfl_xor(r.y, 32, 64);
    r.z += __shfl_xor(r.z, 16, 64); r.z += __shfl_xor(r.z, 32, 64);
    r.w += __shfl_xor(r.w, 16, 64); r.w += __shfl_xor(r.w, 32, 64);
    if (lane < 16) {
        float4 b4 = ((const float4*)bias)[lane];
        float4 o = make_float4(fmaxf(r.x + b4.x, 0.f), fmaxf(r.y + b4.y, 0.f),
                               fmaxf(r.z + b4.z, 0.f), fmaxf(r.w + b4.w, 0.f));
        ((float4*)hout)[(size_t)n * 16 + lane] = o;
    }
}

// ---------------------------------------------------------------------------
extern "C" void kernel_launch(void* const* d_in, const int* in_sizes, int n_in,
                              void* d_out, int out_size, void* d_ws, size_t ws_size,
                              hipStream_t stream) {
    const float* x     = (const float*)d_in[0];
    const float* eattr = (const float*)d_in[1];
    const int*   eidx  = (const int*)d_in[2];
    const float* fW    = (const float*)d_in[3];
    const float* fb    = (const float*)d_in[4];
    const float* feW   = (const float*)d_in[5];
    const float* feb   = (const float*)d_in[6];
    const float* Wl    = (const float*)d_in[7];
    const float* bl    = (const float*)d_in[8];
    const float* Wr    = (const float*)d_in[9];
    const float* br    = (const float*)d_in[10];
    const float* We    = (const float*)d_in[11];
    const float* att   = (const float*)d_in[12];
    const float* bias  = (const float*)d_in[13];
    float* out = (float*)d_out;

    const int N = in_sizes[0] / 128;   // 50000
    const int E = in_sizes[1] / 2;     // 800000
    const int* srcArr = eidx;
    const int* dstArr = eidx + E;

    char* p = (char*)d_ws;
    auto alloc = [&](size_t bytes) -> char* {
        char* r = p;
        p += (bytes + 255) & ~(size_t)255;
        return r;
    };
    float* hA   = (float*)alloc((size_t)N * 64 * 4);
    float* hB   = (float*)alloc((size_t)N * 64 * 4);
    float* xl   = (float*)alloc((size_t)N * 256 * 4);
    float* xr   = (float*)alloc((size_t)N * 256 * 4);
    int* deg    = (int*)alloc((size_t)N * 4);
    int* start  = (int*)alloc((size_t)N * 4);
    int* cursor = (int*)alloc((size_t)N * 4);
    int* counter = (int*)alloc(256);
    int* rec    = (int*)alloc((size_t)(E + 4) * 24 * 4);

    k_h0<<<N / 8, 256, 0, stream>>>(x, fW, fb, hA);
    k_zero<<<(N + 255) / 256, 256, 0, stream>>>(deg, counter, rec, N, E);
    k_count<<<(E + 255) / 256, 256, 0, stream>>>(dstArr, deg, E);
    k_alloc<<<(N + 255) / 256, 256, 0, stream>>>(deg, counter, start, cursor, N);
    k_fill<<<(E + 255) / 256, 256, 0, stream>>>(dstArr, srcArr, eattr, feW, feb,
                                                cursor, rec, E);

    const float* hin = hA;
    for (int layer = 0; layer < 3; ++layer) {
        float* hout = (layer == 2) ? out : ((layer == 0) ? hB : hA);
        k_xlxr<<<N / 16, 256, 0, stream>>>(hin, Wl, Wr, bl, br, xl, xr);
        k_edge<<<(N * 64) / 256, 256, 0, stream>>>(
            (const float4*)xl, (const float4*)xr, att, (const float4*)We,
            rec, start, deg, bias, hout, N);
        hin = hout;
    }
}

// Round 10
// 966.663 us; speedup vs baseline: 1.3379x; 1.3379x over previous
//
#include <hip/hip_runtime.h>
#include <math.h>

typedef float v2f __attribute__((ext_vector_type(2)));

#define LN2_INV 1.4426950408889634f

__device__ __forceinline__ float fexp2(float x) {
#if __has_builtin(__builtin_amdgcn_exp2f)
    return __builtin_amdgcn_exp2f(x);
#else
    return exp2f(x);
#endif
}

__device__ __forceinline__ int rdlane_i(int v, int k) {
    return __builtin_amdgcn_readlane(v, k);
}

// packed f32 VOP3P (assemble+numerics proven on gfx950, R4-R7)
__device__ __forceinline__ v2f pk_fma(v2f a, v2f b, v2f c) {
    asm("v_pk_fma_f32 %0, %1, %2, %0" : "+v"(c) : "v"(a), "v"(b));
    return c;
}
__device__ __forceinline__ v2f pk_fma_s(v2f a_s, v2f b, v2f c) {
    asm("v_pk_fma_f32 %0, %1, %2, %0" : "+v"(c) : "s"(a_s), "v"(b));
    return c;
}
__device__ __forceinline__ v2f pk_mul_s(v2f a_s, v2f b) {
    v2f d;
    asm("v_pk_mul_f32 %0, %1, %2" : "=v"(d) : "s"(a_s), "v"(b));
    return d;
}

// v += dpp(v): row_ror rotate-accumulate (numerics verified in R9 run).
// ror 1/2/4/8 over 16-lane rows = every lane gets the full 16-lane sum.
// Zero LDS/lgkm ops -- replaces shr-prefix + ds_bpermute broadcast.
#define DPP_ADD(V, CTRL) \
    V += __int_as_float(__builtin_amdgcn_update_dpp(0, __float_as_int(V), CTRL, 0xf, 0xf, true));

// ---------------------------------------------------------------------------
// k_h0: h0 = relu(x @ f_W + f_b), x [N,128], f_W [128,64]. 8 nodes/block.
// ---------------------------------------------------------------------------
__global__ __launch_bounds__(256) void k_h0(const float* __restrict__ x,
                                            const float* __restrict__ fW,
                                            const float* __restrict__ fb,
                                            float* __restrict__ h0) {
    __shared__ __align__(16) float xs[8 * 128];
    int t = threadIdx.x;
    int base = blockIdx.x * 8;
#pragma unroll
    for (int r = 0; r < 4; ++r) { int j = r * 256 + t; xs[j] = x[base * 128 + j]; }
    __syncthreads();
    int c = t & 63, half = t >> 6;
    float acc0 = fb[c], acc1 = fb[c];
    int m0 = half, m1 = half + 4;
#pragma unroll 8
    for (int k0 = 0; k0 < 128; k0 += 4) {
        float4 a = *(const float4*)&xs[m0 * 128 + k0];
        float4 b = *(const float4*)&xs[m1 * 128 + k0];
        float w0 = fW[(k0 + 0) * 64 + c], w1 = fW[(k0 + 1) * 64 + c];
        float w2 = fW[(k0 + 2) * 64 + c], w3 = fW[(k0 + 3) * 64 + c];
        acc0 = fmaf(a.x, w0, fmaf(a.y, w1, fmaf(a.z, w2, fmaf(a.w, w3, acc0))));
        acc1 = fmaf(b.x, w0, fmaf(b.y, w1, fmaf(b.z, w2, fmaf(b.w, w3, acc1))));
    }
    h0[(base + m0) * 64 + c] = fmaxf(acc0, 0.f);
    h0[(base + m1) * 64 + c] = fmaxf(acc1, 0.f);
}

// ---------------------------------------------------------------------------
// k_xlxr: xl = h@Wl + bl, xr = h@Wr + br, natural [N][256] layout (h*64+d).
// ---------------------------------------------------------------------------
__global__ __launch_bounds__(256) void k_xlxr(const float* __restrict__ h,
                                              const float* __restrict__ Wl,
                                              const float* __restrict__ Wr,
                                              const float* __restrict__ bl,
                                              const float* __restrict__ br,
                                              float* __restrict__ xl,
                                              float* __restrict__ xr) {
    __shared__ __align__(16) float hs[16 * 64];
    int t = threadIdx.x;
    int base = blockIdx.x * 16;
#pragma unroll
    for (int r = 0; r < 4; ++r) hs[r * 256 + t] = h[base * 64 + r * 256 + t];
    __syncthreads();
    float bL = bl[t], bR = br[t];
    float accl[16], accr[16];
#pragma unroll
    for (int m = 0; m < 16; ++m) { accl[m] = bL; accr[m] = bR; }
#pragma unroll 4
    for (int k0 = 0; k0 < 64; k0 += 4) {
        float wl[4], wr[4];
#pragma unroll
        for (int q = 0; q < 4; ++q) {
            wl[q] = Wl[(k0 + q) * 256 + t];
            wr[q] = Wr[(k0 + q) * 256 + t];
        }
#pragma unroll
        for (int m = 0; m < 16; ++m) {
            float4 hv = *(const float4*)&hs[m * 64 + k0];
            accl[m] = fmaf(hv.x, wl[0], fmaf(hv.y, wl[1], fmaf(hv.z, wl[2], fmaf(hv.w, wl[3], accl[m]))));
            accr[m] = fmaf(hv.x, wr[0], fmaf(hv.y, wr[1], fmaf(hv.z, wr[2], fmaf(hv.w, wr[3], accr[m]))));
        }
    }
#pragma unroll
    for (int m = 0; m < 16; ++m) {
        xl[(base + m) * 256 + t] = accl[m];
        xr[(base + m) * 256 + t] = accr[m];
    }
}

// ---------------------------------------------------------------------------
// CSR build. rec record (stride 24 ints): [0..19] = relu edge-MLP s_k,
// [20] = src node, [21..23] pad. Written at the CSR position directly.
// (R1/R7 layout: lowest HBM fetch, 440 MB.)
// ---------------------------------------------------------------------------
__global__ void k_zero(int* __restrict__ deg, int* __restrict__ counter, int Nn) {
    int i = blockIdx.x * 256 + threadIdx.x;
    if (i < Nn) deg[i] = 0;
    if (i == 0) *counter = 0;
}

__global__ void k_count(const int* __restrict__ dstArr, int* __restrict__ deg, int Ee) {
    int e = blockIdx.x * 256 + threadIdx.x;
    if (e < Ee) atomicAdd(&deg[dstArr[e]], 1);
}

__global__ void k_alloc(const int* __restrict__ deg, int* __restrict__ counter,
                        int* __restrict__ start, int* __restrict__ cursor, int Nn) {
    int n = blockIdx.x * 256 + threadIdx.x;
    if (n < Nn) {
        int d = deg[n];
        int b = atomicAdd(counter, d);
        start[n] = b;
        cursor[n] = b;
    }
}

__global__ void k_fill(const int* __restrict__ dstArr, const int* __restrict__ srcArr,
                       const float* __restrict__ eattr, const float* __restrict__ feW,
                       const float* __restrict__ feb, int* __restrict__ cursor,
                       int* __restrict__ rec, int Ee) {
    int e = blockIdx.x * 256 + threadIdx.x;
    if (e >= Ee) return;
    float a0 = eattr[2 * e], a1 = eattr[2 * e + 1];
    int p = atomicAdd(&cursor[dstArr[e]], 1);
    float* r = (float*)(rec + (size_t)p * 24);
    float s[20];
#pragma unroll
    for (int k = 0; k < 20; ++k)
        s[k] = fmaxf(fmaf(a0, feW[k], fmaf(a1, feW[20 + k], feb[k])), 0.f);
#pragma unroll
    for (int j = 0; j < 5; ++j)
        ((float4*)r)[j] = make_float4(s[4 * j], s[4 * j + 1], s[4 * j + 2], s[4 * j + 3]);
    ((int*)r)[20] = srcArr[e];
}

// ---------------------------------------------------------------------------
// k_edge: R7 verbatim (one wave per dst node; record read 1 dword/lane,
// readlane broadcasts into pk_fma with SGPR-pair source; records 3 ahead,
// xl gathers 2 ahead) with ONE change: the score reduce is 4x DPP row_ror
// adds (all-reduce in registers) instead of shr-prefix + ds_bpermute.
// The loop now contains ZERO lgkm ops -> no per-edge lgkmcnt(0) drain on
// the serial score->exp2 chain (R7's only remaining lgkm stall source).
// ---------------------------------------------------------------------------
__global__ __launch_bounds__(256, 3) void k_edge(
    const float4* __restrict__ xl4p, const float4* __restrict__ xr4p,
    const float* __restrict__ att, const float4* __restrict__ We4,
    const int* __restrict__ rec, const int* __restrict__ start,
    const int* __restrict__ deg, const float* __restrict__ bias,
    float* __restrict__ hout, int Nn) {
    const int lane = threadIdx.x & 63;
    const int n = (int)((blockIdx.x * 256u + threadIdx.x) >> 6);
    if (n >= Nn) return;

    const int dn = __builtin_amdgcn_readfirstlane(deg[n]);
    float4 bias4 = ((const float4*)bias)[lane & 15];
    if (dn == 0) {
        if (lane < 16) {
            float4 o = make_float4(fmaxf(bias4.x, 0.f), fmaxf(bias4.y, 0.f),
                                   fmaxf(bias4.z, 0.f), fmaxf(bias4.w, 0.f));
            ((float4*)hout)[(size_t)n * 16 + lane] = o;
        }
        return;
    }
    const int s0 = __builtin_amdgcn_readfirstlane(start[n]);
    const int* rb = rec + (size_t)s0 * 24 + (lane & 31);

    // wave-invariant operands
    float4 attv = ((const float4*)att)[lane];
    float at0 = attv.x * LN2_INV, at1 = attv.y * LN2_INV;
    float at2 = attv.z * LN2_INV, at3 = attv.w * LN2_INV;
    float4 xrv = xr4p[(size_t)n * 64 + lane];
    // We, k-interleaved per dim: weI_d[p] = {We[2p][d], We[2p+1][d]}
    v2f weI0[10], weI1[10], weI2[10], weI3[10];
#pragma unroll
    for (int p = 0; p < 10; ++p) {
        float4 w0 = We4[(2 * p) * 64 + lane];
        float4 w1 = We4[(2 * p + 1) * 64 + lane];
        weI0[p].x = w0.x; weI0[p].y = w1.x;
        weI1[p].x = w0.y; weI1[p].y = w1.y;
        weI2[p].x = w0.z; weI2[p].y = w1.z;
        weI3[p].x = w0.w; weI3[p].y = w1.w;
    }

    v2f acc01 = {0.f, 0.f}, acc23 = {0.f, 0.f};
    float l = 0.f;

    // prologue: records for edges 0,1,2; xl gathers for edges 0,1
    int i1 = dn > 1 ? 1 : 0;
    int i2p = dn > 2 ? 2 : (dn - 1);
    int rv0 = rb[0];
    int rv1 = rb[(size_t)i1 * 24];
    int rv2 = rb[(size_t)i2p * 24];
    int src0 = rdlane_i(rv0, 20);
    float4 xl0 = xl4p[(unsigned)(src0 * 64 + lane)];
    int src1 = rdlane_i(rv1, 20);
    float4 xl1 = xl4p[(unsigned)(src1 * 64 + lane)];

    for (int i = 0; i < dn; ++i) {
        // prefetch: record i+3, xl gather i+2 (uses rv2, loaded last iter)
        int i3 = (i + 3 < dn) ? (i + 3) : (dn - 1);
        int rvN = rb[(size_t)i3 * 24];
        int src2 = rdlane_i(rv2, 20);
        float4 xl2 = xl4p[(unsigned)(src2 * 64 + lane)];

        // ee matvec: 10 SGPR pairs {s_2p, s_2p+1} x 4 dim-groups of pk_fma
        v2f a0, a1, a2, a3;
        {
            v2f sp;
            sp.x = __int_as_float(rdlane_i(rv0, 0));
            sp.y = __int_as_float(rdlane_i(rv0, 1));
            a0 = pk_mul_s(sp, weI0[0]);
            a1 = pk_mul_s(sp, weI1[0]);
            a2 = pk_mul_s(sp, weI2[0]);
            a3 = pk_mul_s(sp, weI3[0]);
        }
#pragma unroll
        for (int p = 1; p < 10; ++p) {
            v2f sp;
            sp.x = __int_as_float(rdlane_i(rv0, 2 * p));
            sp.y = __int_as_float(rdlane_i(rv0, 2 * p + 1));
            a0 = pk_fma_s(sp, weI0[p], a0);
            a1 = pk_fma_s(sp, weI1[p], a1);
            a2 = pk_fma_s(sp, weI2[p], a2);
            a3 = pk_fma_s(sp, weI3[p], a3);
        }
        float v0 = (xl0.x + xrv.x) + (a0.x + a0.y);
        float v1 = (xl0.y + xrv.y) + (a1.x + a1.y);
        float v2 = (xl0.z + xrv.z) + (a2.x + a2.y);
        float v3 = (xl0.w + xrv.w) + (a3.x + a3.y);
        float m0 = fmaxf(v0, 0.2f * v0);
        float m1 = fmaxf(v1, 0.2f * v1);
        float m2 = fmaxf(v2, 0.2f * v2);
        float m3 = fmaxf(v3, 0.2f * v3);
        float ps = fmaf(at0, m0, fmaf(at1, m1, fmaf(at2, m2, at3 * m3)));
        DPP_ADD(ps, 0x121)
        DPP_ADD(ps, 0x122)
        DPP_ADD(ps, 0x124)
        DPP_ADD(ps, 0x128)
        float w_ = fexp2(ps);
        l += w_;
        v2f w2 = {w_, w_};
        v2f xl01 = {xl0.x, xl0.y}, xl23 = {xl0.z, xl0.w};
        acc01 = pk_fma(w2, xl01, acc01);
        acc23 = pk_fma(w2, xl23, acc23);

        rv0 = rv1; rv1 = rv2; rv2 = rvN;
        xl0 = xl1; xl1 = xl2;
    }

    // epilogue: res = relu(bias + 0.25 * sum_h acc_h / l_h)
    float inv = 0.25f / l;
    float4 r = make_float4(acc01.x * inv, acc01.y * inv, acc23.x * inv, acc23.y * inv);
    r.x += __shfl_xor(r.x, 16, 64); r.x += __shfl_xor(r.x, 32, 64);
    r.y += __shfl_xor(r.y, 16, 64); r.y += __shfl_xor(r.y, 32, 64);
    r.z += __shfl_xor(r.z, 16, 64); r.z += __shfl_xor(r.z, 32, 64);
    r.w += __shfl_xor(r.w, 16, 64); r.w += __shfl_xor(r.w, 32, 64);
    if (lane < 16) {
        float4 o = make_float4(fmaxf(r.x + bias4.x, 0.f), fmaxf(r.y + bias4.y, 0.f),
                               fmaxf(r.z + bias4.z, 0.f), fmaxf(r.w + bias4.w, 0.f));
        ((float4*)hout)[(size_t)n * 16 + lane] = o;
    }
}

// ---------------------------------------------------------------------------
extern "C" void kernel_launch(void* const* d_in, const int* in_sizes, int n_in,
                              void* d_out, int out_size, void* d_ws, size_t ws_size,
                              hipStream_t stream) {
    const float* x     = (const float*)d_in[0];
    const float* eattr = (const float*)d_in[1];
    const int*   eidx  = (const int*)d_in[2];
    const float* fW    = (const float*)d_in[3];
    const float* fb    = (const float*)d_in[4];
    const float* feW   = (const float*)d_in[5];
    const float* feb   = (const float*)d_in[6];
    const float* Wl    = (const float*)d_in[7];
    const float* bl    = (const float*)d_in[8];
    const float* Wr    = (const float*)d_in[9];
    const float* br    = (const float*)d_in[10];
    const float* We    = (const float*)d_in[11];
    const float* att   = (const float*)d_in[12];
    const float* bias  = (const float*)d_in[13];
    float* out = (float*)d_out;

    const int N = in_sizes[0] / 128;   // 50000
    const int E = in_sizes[1] / 2;     // 800000
    const int* srcArr = eidx;
    const int* dstArr = eidx + E;

    char* p = (char*)d_ws;
    auto alloc = [&](size_t bytes) -> char* {
        char* r = p;
        p += (bytes + 255) & ~(size_t)255;
        return r;
    };
    float* hA   = (float*)alloc((size_t)N * 64 * 4);
    float* hB   = (float*)alloc((size_t)N * 64 * 4);
    float* xl   = (float*)alloc((size_t)N * 256 * 4);
    float* xr   = (float*)alloc((size_t)N * 256 * 4);
    int* deg    = (int*)alloc((size_t)N * 4);
    int* start  = (int*)alloc((size_t)N * 4);
    int* cursor = (int*)alloc((size_t)N * 4);
    int* counter = (int*)alloc(256);
    int* rec    = (int*)alloc((size_t)E * 24 * 4);

    k_h0<<<N / 8, 256, 0, stream>>>(x, fW, fb, hA);
    k_zero<<<(N + 255) / 256, 256, 0, stream>>>(deg, counter, N);
    k_count<<<(E + 255) / 256, 256, 0, stream>>>(dstArr, deg, E);
    k_alloc<<<(N + 255) / 256, 256, 0, stream>>>(deg, counter, start, cursor, N);
    k_fill<<<(E + 255) / 256, 256, 0, stream>>>(dstArr, srcArr, eattr, feW, feb,
                                                cursor, rec, E);

    const float* hin = hA;
    for (int layer = 0; layer < 3; ++layer) {
        float* hout = (layer == 2) ? out : ((layer == 0) ? hB : hA);
        k_xlxr<<<N / 16, 256, 0, stream>>>(hin, Wl, Wr, bl, br, xl, xr);
        k_edge<<<(N * 64) / 256, 256, 0, stream>>>(
            (const float4*)xl, (const float4*)xr, att, (const float4*)We,
            rec, start, deg, bias, hout, N);
        hin = hout;
    }
}